// Round 16
// baseline (71.768 us; speedup 1.0000x reference)
//
#include <hip/hip_runtime.h>
#include <hip/hip_bf16.h>
#include <stdint.h>

// FullTucker: Z = U0 @ einsum('pqr,qb,rb->pb', G, U1^T@X1, U2^T@X2)
// D_OUT=D1=D2=512, R0=R1=R2=128, BATCH=8192. f32 in/out; bf16 MFMA inside.
// R16 = R14 k_core (NO setprio -- attribution test vs R15) + R15 k_zred
// (512 blocks, 2/CU, hides cross-XCD PT read latency). castU/ux2g unchanged.

typedef __attribute__((ext_vector_type(8))) short bf8;   // 8 bf16 (4 VGPR)
typedef __attribute__((ext_vector_type(4))) short bf4;   // 4 bf16 (8B)
typedef __attribute__((ext_vector_type(4))) float f4;    // 4 f32

__device__ __forceinline__ unsigned short f2bf(float f){
  unsigned x = __builtin_bit_cast(unsigned, f);
  x += 0x7fffu + ((x >> 16) & 1u);            // RNE (inputs finite)
  return (unsigned short)(x >> 16);
}
__device__ __forceinline__ float bf2f(unsigned short u){
  unsigned x = ((unsigned)u) << 16;
  return __builtin_bit_cast(float, x);
}
__device__ __forceinline__ void glds16(const void* g, void* l){
  __builtin_amdgcn_global_load_lds(
      (const __attribute__((address_space(1))) void*)g,
      (__attribute__((address_space(3))) void*)l, 16, 0, 0);
}

// ---------------- U transpose-cast (must precede k_ux2g) ----------------
__global__ __launch_bounds__(256) void k_castU(const float* __restrict__ U1,
                                               const float* __restrict__ U2,
                                               unsigned short* __restrict__ U1T,
                                               unsigned short* __restrict__ U2T){
  const int b2 = blockIdx.x;                               // 0..511
  const float* U = (b2 < 256) ? U1 : U2;
  unsigned short* UT = (b2 < 256) ? U1T : U2T;
  const int idx = (b2 & 255) * 256 + threadIdx.x;          // 0..65535
  const int d = idx >> 7, q = idx & 127;
  UT[q * 512 + d] = f2bf(U[idx]);
}

// ---------------- UX GEMM + concurrent G/U0 cast (one dispatch) ----------------
// blocks [0,128): UX1 = U1T@X1 (f32 out). [128,256): UX2T (bf16 transposed).
// blocks [256,2368): cast G,U0 -> bf16 (runs concurrently on idle CUs).
__global__ __launch_bounds__(256) void k_ux2g(const unsigned short* __restrict__ U1T,
                                              const unsigned short* __restrict__ U2T,
                                              const float* __restrict__ X1,
                                              const float* __restrict__ X2,
                                              const float* __restrict__ G,
                                              const float* __restrict__ U0,
                                              unsigned short* __restrict__ Gbf,
                                              unsigned short* __restrict__ U0bf,
                                              float* __restrict__ OUTF,
                                              unsigned short* __restrict__ OUTT){
  __shared__ __align__(16) unsigned char lds[16384 + 8192];
  if (blockIdx.x >= 256){
    const int i4 = (blockIdx.x - 256) * 256 + threadIdx.x; // 0..540671
    const int NG4 = 2097152 / 4;
    const float4* src; unsigned short* dst; int j4;
    if (i4 < NG4){ src = (const float4*)G;  dst = Gbf;  j4 = i4; }
    else         { src = (const float4*)U0; dst = U0bf; j4 = i4 - NG4; }
    float4 v = src[j4];
    ushort4 o = make_ushort4(f2bf(v.x), f2bf(v.y), f2bf(v.z), f2bf(v.w));
    ((ushort4*)dst)[j4] = o;
    return;
  }
  const bool second = (blockIdx.x >= 128);
  const unsigned short* UT = second ? U2T : U1T;
  const float* X = second ? X2 : X1;
  unsigned char* ldsA = lds;
  unsigned char* ldsB = lds + 16384;
  const int tid = threadIdx.x, lane = tid & 63, wv = tid >> 6;
  const int wr = wv >> 1, wc = wv & 1;
  const int b0 = (blockIdx.x & 127) * 64;
  f4 acc[4][2] = {};

  for (int it = 0; it < 8; ++it){
    const int k0 = it * 64;
#pragma unroll
    for (int i = 0; i < 4; ++i){
      const int L = (wv * 4 + i) * 1024 + lane * 16;
      const int row = L >> 7;
      const int ss = (lane & 7) ^ (row & 7);
      glds16(UT + (size_t)row * 512 + k0 + ss * 8, ldsA + (wv * 4 + i) * 1024);
    }
#pragma unroll
    for (int c = 0; c < 2; ++c){
      const int slot = c * 4 + wv;
      const int bRow = lane;
      bf8 v;
#pragma unroll
      for (int j = 0; j < 8; ++j)
        v[j] = (short)f2bf(X[(size_t)(k0 + slot * 8 + j) * 8192 + b0 + bRow]);
      *(bf8*)(ldsB + bRow * 128 + ((slot ^ (bRow & 7)) << 4)) = v;
    }
    __syncthreads();
#pragma unroll
    for (int kc = 0; kc < 2; ++kc){
      const int g = lane >> 4;
      bf8 a[4], b[2];
#pragma unroll
      for (int mf = 0; mf < 4; ++mf){
        const int r = wr * 64 + mf * 16 + (lane & 15);
        a[mf] = *(const bf8*)(ldsA + r * 128 + (((kc * 4 + g) ^ (r & 7)) << 4));
      }
#pragma unroll
      for (int nf = 0; nf < 2; ++nf){
        const int rb = wc * 32 + nf * 16 + (lane & 15);
        b[nf] = *(const bf8*)(ldsB + rb * 128 + (((kc * 4 + g) ^ (rb & 7)) << 4));
      }
#pragma unroll
      for (int mf = 0; mf < 4; ++mf)
#pragma unroll
        for (int nf = 0; nf < 2; ++nf)
          acc[mf][nf] = __builtin_amdgcn_mfma_f32_16x16x32_bf16(a[mf], b[nf], acc[mf][nf], 0, 0, 0);
    }
    __syncthreads();
  }

  if (!second){
#pragma unroll
    for (int mf = 0; mf < 4; ++mf)
#pragma unroll
      for (int nf = 0; nf < 2; ++nf)
#pragma unroll
        for (int j = 0; j < 4; ++j){
          const int q = wr * 64 + mf * 16 + (lane >> 4) * 4 + j;
          const int b = b0 + wc * 32 + nf * 16 + (lane & 15);
          OUTF[(size_t)q * 8192 + b] = acc[mf][nf][j];
        }
  } else {
#pragma unroll
    for (int mf = 0; mf < 4; ++mf)
#pragma unroll
      for (int nf = 0; nf < 2; ++nf){
        const int rBase = wr * 64 + mf * 16 + (lane >> 4) * 4;
        const int bL = wc * 32 + nf * 16 + (lane & 15);
        bf4 p;
#pragma unroll
        for (int j = 0; j < 4; ++j) p[j] = (short)f2bf(acc[mf][nf][j]);
        *(bf4*)(lds + ((bL * 256 + rBase * 2) ^ ((bL & 7) << 4))) = p;
      }
    __syncthreads();
#pragma unroll
    for (int u = 0; u < 4; ++u){
      const int sIdx = u * 256 + tid;
      const int bL = sIdx >> 4, slot = sIdx & 15;
      bf8 v = *(const bf8*)(lds + bL * 256 + ((slot ^ (bL & 7)) << 4));
      *(bf8*)(OUTT + (size_t)(b0 + bL) * 128 + slot * 8) = v;
    }
  }
}

// ---------------- core: minimal-fence ring GEMM, 16 waves (4/SIMD), split-K(q)=8 ----------------
// Grid 256 (1 block/CU), 1024 thr = 16 waves (2 wr x 8 wc), wave 64p x 32b
// (mf=4, nf=2). LDS: A ring 3x32KB ([128p][128r] bf16, &15-swizzled) + x1 16KB.
__global__ __launch_bounds__(1024) void k_core(const unsigned short* __restrict__ Gbf,  // [128][16384]
                                               const float* __restrict__ UX1,           // [128][8192]
                                               const unsigned short* __restrict__ UX2T, // [8192][128]
                                               unsigned short* __restrict__ PT){        // [8][8192][128] bf16
  __shared__ __align__(16) unsigned char lds[114688];      // 3x32K ring + 16K x1
  unsigned char* ldsX = lds + 98304;
  const int tid = threadIdx.x, lane = tid & 63, wv = tid >> 6;
  const int g = lane >> 4, l15 = lane & 15;
  const int wr = wv >> 3, wc = wv & 7;          // 2 p-strips x 8 b-strips
  const int blk = blockIdx.x;                   // 0..255; round-robin => xcd = blk&7
  const int split = blk & 7;                    // one split per XCD (G slice 512KB, L2-res)
  const int b0 = (blk >> 3) * 256;              // 0..7936
  const int q0 = split * 16;

  // stage one 32KB q-slice [128p][128r] into ring buf (2 glds16 per thread).
  // &15 source pre-swizzle matches &15 read XOR (R10-measured ~0 conflicts).
  auto stageA = [&](int q, int buf){
#pragma unroll
    for (int rnd = 0; rnd < 2; ++rnd){
      const int off = rnd * 16384 + tid * 16;
      const int row = off >> 8;                 // p-row 0..127
      const int ss = ((off >> 4) & 15) ^ (row & 15);  // source pre-swizzle
      glds16(Gbf + (size_t)row * 16384 + (size_t)q * 128 + ss * 8,
             lds + buf * 32768 + off);
    }
  };

  // B hoist FIRST: Bf[kc][nf] = 8 bf8 = 32 VGPR, whole kernel
  bf8 Bf[4][2];
#pragma unroll
  for (int kc = 0; kc < 4; ++kc)
#pragma unroll
    for (int nf = 0; nf < 2; ++nf)
      Bf[kc][nf] = *(const bf8*)(UX2T + (size_t)(b0 + wc * 32 + nf * 16 + l15) * 128 +
                                 kc * 32 + g * 8);
  // x1 slice [16q][256b] f32 -> LDS (1 glds per thread)
  {
    const int off = tid * 16;
    const int row = off >> 10;                  // q-row 0..15
    glds16(UX1 + (size_t)(q0 + row) * 8192 + b0 + ((off >> 2) & 255), ldsX + off);
  }
  stageA(q0 + 0, 0);
  stageA(q0 + 1, 1);

  f4 acc[4][2];
#pragma unroll
  for (int mf = 0; mf < 4; ++mf)
#pragma unroll
    for (int nf = 0; nf < 2; ++nf) acc[mf][nf] = (f4){0.f, 0.f, 0.f, 0.f};

  int cur = 0;                                  // ring buffer of body(i)
  for (int i = 0; i < 16; ++i){
    // ONE counted wait + ONE barrier per q. Per-wave outstanding at top:
    // stage(i)[2] + stage(i+1)[2] -> vmcnt(2) retires stage(i) (and x1 at i=0).
    if (i < 15) asm volatile("s_waitcnt vmcnt(2)" ::: "memory");
    else        asm volatile("s_waitcnt vmcnt(0)" ::: "memory");
    __builtin_amdgcn_s_barrier();
    if (i < 14){
      int sbuf = cur + 2; if (sbuf >= 3) sbuf -= 3;
      stageA(q0 + i + 2, sbuf);
    }

    // ---- body: pure C++, compiler-scheduled (fine lgkmcnt, MFMA interleave)
    const unsigned char* A = lds + cur * 32768;
    float xs[2];
#pragma unroll
    for (int nf = 0; nf < 2; ++nf)
      xs[nf] = *(const float*)(ldsX + i * 1024 + (wc * 32 + nf * 16 + l15) * 4);
#pragma unroll
    for (int mf = 0; mf < 4; ++mf){
      const int row = wr * 64 + mf * 16 + l15;  // row & 15 == l15
      bf8 a[4];
#pragma unroll
      for (int kc = 0; kc < 4; ++kc)
        a[kc] = *(const bf8*)(A + row * 256 + ((((kc << 2) + g) ^ l15) << 4));
#pragma unroll
      for (int nf = 0; nf < 2; ++nf){
        f4 y = __builtin_amdgcn_mfma_f32_16x16x32_bf16(a[0], Bf[0][nf], (f4){0.f,0.f,0.f,0.f}, 0, 0, 0);
        y = __builtin_amdgcn_mfma_f32_16x16x32_bf16(a[1], Bf[1][nf], y, 0, 0, 0);
        y = __builtin_amdgcn_mfma_f32_16x16x32_bf16(a[2], Bf[2][nf], y, 0, 0, 0);
        y = __builtin_amdgcn_mfma_f32_16x16x32_bf16(a[3], Bf[3][nf], y, 0, 0, 0);
        acc[mf][nf] += y * xs[nf];              // fold x1 in f32 (chain tail)
      }
    }
    ++cur; if (cur == 3) cur = 0;
  }

  // epilogue: acc -> PT[split][b][p] bf16 via swizzled LDS transpose (64KB in ring)
  __syncthreads();
#pragma unroll
  for (int mf = 0; mf < 4; ++mf)
#pragma unroll
    for (int nf = 0; nf < 2; ++nf){
      const int bL = wc * 32 + nf * 16 + l15;    // 0..255
      const int pq = wr * 16 + mf * 4 + g;       // p-quad 0..31
      bf4 o;
#pragma unroll
      for (int j = 0; j < 4; ++j) o[j] = (short)f2bf(acc[mf][nf][j]);
      *(bf4*)(lds + bL * 256 + ((pq ^ (bL & 7)) << 3)) = o;
    }
  __syncthreads();
#pragma unroll
  for (int rnd = 0; rnd < 4; ++rnd){
    const int idx = rnd * 1024 + tid;            // 4096 x 16B chunks
    const int bL = idx >> 4, s8 = idx & 15;
    bf4 lo = *(const bf4*)(lds + bL * 256 + (((s8 * 2) ^ (bL & 7)) << 3));
    bf4 hi = *(const bf4*)(lds + bL * 256 + (((s8 * 2 + 1) ^ (bL & 7)) << 3));
    bf8 o;
#pragma unroll
    for (int j = 0; j < 4; ++j){ o[j] = lo[j]; o[4 + j] = hi[j]; }
    *(bf8*)(PT + (size_t)split * 1048576 + (size_t)(b0 + bL) * 128 + s8 * 8) = o;
  }
}

// ---------------- fused reduce + Z GEMM (512 blocks, 16-b columns, 2/CU) ----------------
// Block = 512 thr (8 waves), 512 d x 16 b. (1) 256 threads reduce 8 PT
// partials -> ldsB [16b][128k] bf16 swizzled; (2) per-wave U0 A-frags from L2;
// (3) one barrier, 16 MFMA/wave, direct f32 Z stores.
__global__ __launch_bounds__(512, 1) void k_zred(const unsigned short* __restrict__ U0bf, // [512][128]
                                                 const unsigned short* __restrict__ PT,   // [8][8192][128]
                                                 float* __restrict__ Z){                  // [512][8192]
  __shared__ __align__(16) unsigned char ldsB[4096];       // [16b][128k] bf16 swizzled
  const int tid = threadIdx.x, lane = tid & 63, wv = tid >> 6;
  const int g = lane >> 4, l15 = lane & 15;
  const int b0 = blockIdx.x * 16;

  // (1) reduce: threads [0,256): b = t>>4 (0..15), slot = t&15 (8 k each)
  if (tid < 256){
    const int b = tid >> 4, slot = tid & 15;
    float s[8] = {0.f, 0.f, 0.f, 0.f, 0.f, 0.f, 0.f, 0.f};
#pragma unroll
    for (int sp = 0; sp < 8; ++sp){
      bf8 v = *(const bf8*)(PT + ((size_t)sp * 8192 + b0 + b) * 128 + slot * 8);
#pragma unroll
      for (int j = 0; j < 8; ++j) s[j] += bf2f((unsigned short)v[j]);
    }
    bf8 o;
#pragma unroll
    for (int j = 0; j < 8; ++j) o[j] = (short)f2bf(s[j]);
    *(bf8*)(ldsB + b * 256 + ((slot ^ b) << 4)) = o;
  }

  // (2) A frags: wave wv owns d-rows [wv*64, wv*64+64); 16 bf8 = 64 VGPR
  bf8 a[4][4];                                   // [mf][kc]
#pragma unroll
  for (int mf = 0; mf < 4; ++mf)
#pragma unroll
    for (int kc = 0; kc < 4; ++kc)
      a[mf][kc] = *(const bf8*)(U0bf + (size_t)(wv * 64 + mf * 16 + l15) * 128 +
                                kc * 32 + g * 8);

  __syncthreads();

  // (3) GEMM: K=128 (4 kc), wave tile 64d x 16b (mf=4, nf=1)
  bf8 bfr[4];
  const int row = l15;                           // b index 0..15
#pragma unroll
  for (int kc = 0; kc < 4; ++kc)
    bfr[kc] = *(const bf8*)(ldsB + row * 256 + ((((kc << 2) + g) ^ row) << 4));
  f4 acc[4];
#pragma unroll
  for (int mf = 0; mf < 4; ++mf){
    f4 y = __builtin_amdgcn_mfma_f32_16x16x32_bf16(a[mf][0], bfr[0], (f4){0.f,0.f,0.f,0.f}, 0, 0, 0);
    y = __builtin_amdgcn_mfma_f32_16x16x32_bf16(a[mf][1], bfr[1], y, 0, 0, 0);
    y = __builtin_amdgcn_mfma_f32_16x16x32_bf16(a[mf][2], bfr[2], y, 0, 0, 0);
    y = __builtin_amdgcn_mfma_f32_16x16x32_bf16(a[mf][3], bfr[3], y, 0, 0, 0);
    acc[mf] = y;
  }

  // (4) store Z[d][b] f32 (C/D: b-col = l15, d-rows = g*4+j)
#pragma unroll
  for (int mf = 0; mf < 4; ++mf)
#pragma unroll
    for (int j = 0; j < 4; ++j){
      const int d = wv * 64 + mf * 16 + g * 4 + j;
      const int b = b0 + l15;
      Z[(size_t)d * 8192 + b] = acc[mf][j];
    }
}

// ---------------- host launch ----------------
extern "C" void kernel_launch(void* const* d_in, const int* in_sizes, int n_in,
                              void* d_out, int out_size, void* d_ws, size_t ws_size,
                              hipStream_t stream){
  const float* X1 = (const float*)d_in[0];
  const float* X2 = (const float*)d_in[1];
  const float* U0 = (const float*)d_in[2];
  const float* U1 = (const float*)d_in[3];
  const float* U2 = (const float*)d_in[4];
  const float* G  = (const float*)d_in[5];
  float* Z = (float*)d_out;

  char* ws = (char*)d_ws;
  unsigned short* Gbf   = (unsigned short*)(ws);              //  4,194,304 B
  unsigned short* U0bf  = (unsigned short*)(ws + 4194304);    //    131,072 B
  unsigned short* U1T   = (unsigned short*)(ws + 4325376);    //    131,072 B
  unsigned short* U2T   = (unsigned short*)(ws + 4456448);    //    131,072 B
  float*          UX1   = (float*)         (ws + 4587520);    //  4,194,304 B
  unsigned short* UX2T  = (unsigned short*)(ws + 8781824);    //  2,097,152 B
  unsigned short* PT    = (unsigned short*)(ws + 12976128);   // 16,777,216 B (bf16 x8 splits)

  k_castU<<<dim3(512),  dim3(256), 0, stream>>>(U1, U2, U1T, U2T);
  k_ux2g <<<dim3(2368), dim3(256), 0, stream>>>(U1T, U2T, X1, X2, G, U0,
                                                Gbf, U0bf, UX1, UX2T);
  k_core <<<dim3(256), dim3(1024), 0, stream>>>(Gbf, UX1, UX2T, PT);
  k_zred <<<dim3(512), dim3(512), 0, stream>>>(U0bf, PT, Z);
}

// Round 17
// 68.698 us; speedup vs baseline: 1.0447x; 1.0447x over previous
//
#include <hip/hip_runtime.h>
#include <hip/hip_bf16.h>
#include <stdint.h>

// FullTucker: Z = U0 @ einsum('pqr,qb,rb->pb', G, U1^T@X1, U2^T@X2)
// D_OUT=D1=D2=512, R0=R1=R2=128, BATCH=8192. f32 in/out; bf16 MFMA inside.
// R17 = R13 (best measured: 68.9us) + the &15 LDS swizzle in k_core
// (isolated twice-measured fix: 2.2M -> ~0.13M bank conflicts on this
// exact access shape). zred stays 256 blocks (zred-512 was the R15/R16
// regression: doubles redundant U0 reads).

typedef __attribute__((ext_vector_type(8))) short bf8;   // 8 bf16 (4 VGPR)
typedef __attribute__((ext_vector_type(4))) short bf4;   // 4 bf16 (8B)
typedef __attribute__((ext_vector_type(4))) float f4;    // 4 f32

__device__ __forceinline__ unsigned short f2bf(float f){
  unsigned x = __builtin_bit_cast(unsigned, f);
  x += 0x7fffu + ((x >> 16) & 1u);            // RNE (inputs finite)
  return (unsigned short)(x >> 16);
}
__device__ __forceinline__ float bf2f(unsigned short u){
  unsigned x = ((unsigned)u) << 16;
  return __builtin_bit_cast(float, x);
}
__device__ __forceinline__ void glds16(const void* g, void* l){
  __builtin_amdgcn_global_load_lds(
      (const __attribute__((address_space(1))) void*)g,
      (__attribute__((address_space(3))) void*)l, 16, 0, 0);
}

// ---------------- merged cast kernel ----------------
__global__ __launch_bounds__(256) void k_cast(const float* __restrict__ G,
                                              const float* __restrict__ U0,
                                              const float* __restrict__ U1,
                                              const float* __restrict__ U2,
                                              unsigned short* __restrict__ Gbf,
                                              unsigned short* __restrict__ U0bf,
                                              unsigned short* __restrict__ U1T,
                                              unsigned short* __restrict__ U2T){
  const int blk = blockIdx.x;
  if (blk < 2112){
    const int i4 = blk * 256 + threadIdx.x;                // 0..540671
    const int NG4 = 2097152 / 4;
    const float4* src; unsigned short* dst; int j4;
    if (i4 < NG4){ src = (const float4*)G;  dst = Gbf;  j4 = i4; }
    else         { src = (const float4*)U0; dst = U0bf; j4 = i4 - NG4; }
    float4 v = src[j4];
    ushort4 o = make_ushort4(f2bf(v.x), f2bf(v.y), f2bf(v.z), f2bf(v.w));
    ((ushort4*)dst)[j4] = o;
  } else {
    const int b2 = blk - 2112;                             // 0..511
    const float* U = (b2 < 256) ? U1 : U2;
    unsigned short* UT = (b2 < 256) ? U1T : U2T;
    const int idx = (b2 & 255) * 256 + threadIdx.x;        // 0..65535
    const int d = idx >> 7, q = idx & 127;
    UT[q * 512 + d] = f2bf(U[idx]);
  }
}

// ---------------- UX GEMM (both modes, one dispatch) ----------------
__global__ __launch_bounds__(256) void k_ux2(const unsigned short* __restrict__ U1T,
                                             const unsigned short* __restrict__ U2T,
                                             const float* __restrict__ X1,
                                             const float* __restrict__ X2,
                                             float* __restrict__ OUTF,
                                             unsigned short* __restrict__ OUTT){
  const bool second = (blockIdx.y != 0);
  const unsigned short* UT = second ? U2T : U1T;
  const float* X = second ? X2 : X1;
  __shared__ __align__(16) unsigned char lds[16384 + 8192];
  unsigned char* ldsA = lds;
  unsigned char* ldsB = lds + 16384;
  const int tid = threadIdx.x, lane = tid & 63, wv = tid >> 6;
  const int wr = wv >> 1, wc = wv & 1;
  const int b0 = blockIdx.x * 64;
  f4 acc[4][2] = {};

  for (int it = 0; it < 8; ++it){
    const int k0 = it * 64;
#pragma unroll
    for (int i = 0; i < 4; ++i){
      const int L = (wv * 4 + i) * 1024 + lane * 16;
      const int row = L >> 7;
      const int ss = (lane & 7) ^ (row & 7);
      glds16(UT + (size_t)row * 512 + k0 + ss * 8, ldsA + (wv * 4 + i) * 1024);
    }
#pragma unroll
    for (int c = 0; c < 2; ++c){
      const int slot = c * 4 + wv;
      const int bRow = lane;
      bf8 v;
#pragma unroll
      for (int j = 0; j < 8; ++j)
        v[j] = (short)f2bf(X[(size_t)(k0 + slot * 8 + j) * 8192 + b0 + bRow]);
      *(bf8*)(ldsB + bRow * 128 + ((slot ^ (bRow & 7)) << 4)) = v;
    }
    __syncthreads();
#pragma unroll
    for (int kc = 0; kc < 2; ++kc){
      const int g = lane >> 4;
      bf8 a[4], b[2];
#pragma unroll
      for (int mf = 0; mf < 4; ++mf){
        const int r = wr * 64 + mf * 16 + (lane & 15);
        a[mf] = *(const bf8*)(ldsA + r * 128 + (((kc * 4 + g) ^ (r & 7)) << 4));
      }
#pragma unroll
      for (int nf = 0; nf < 2; ++nf){
        const int rb = wc * 32 + nf * 16 + (lane & 15);
        b[nf] = *(const bf8*)(ldsB + rb * 128 + (((kc * 4 + g) ^ (rb & 7)) << 4));
      }
#pragma unroll
      for (int mf = 0; mf < 4; ++mf)
#pragma unroll
        for (int nf = 0; nf < 2; ++nf)
          acc[mf][nf] = __builtin_amdgcn_mfma_f32_16x16x32_bf16(a[mf], b[nf], acc[mf][nf], 0, 0, 0);
    }
    __syncthreads();
  }

  if (!second){
#pragma unroll
    for (int mf = 0; mf < 4; ++mf)
#pragma unroll
      for (int nf = 0; nf < 2; ++nf)
#pragma unroll
        for (int j = 0; j < 4; ++j){
          const int q = wr * 64 + mf * 16 + (lane >> 4) * 4 + j;
          const int b = b0 + wc * 32 + nf * 16 + (lane & 15);
          OUTF[(size_t)q * 8192 + b] = acc[mf][nf][j];
        }
  } else {
#pragma unroll
    for (int mf = 0; mf < 4; ++mf)
#pragma unroll
      for (int nf = 0; nf < 2; ++nf){
        const int rBase = wr * 64 + mf * 16 + (lane >> 4) * 4;
        const int bL = wc * 32 + nf * 16 + (lane & 15);
        bf4 p;
#pragma unroll
        for (int j = 0; j < 4; ++j) p[j] = (short)f2bf(acc[mf][nf][j]);
        *(bf4*)(lds + ((bL * 256 + rBase * 2) ^ ((bL & 7) << 4))) = p;
      }
    __syncthreads();
#pragma unroll
    for (int u = 0; u < 4; ++u){
      const int sIdx = u * 256 + tid;
      const int bL = sIdx >> 4, slot = sIdx & 15;
      bf8 v = *(const bf8*)(lds + bL * 256 + ((slot ^ (bL & 7)) << 4));
      *(bf8*)(OUTT + (size_t)(b0 + bL) * 128 + slot * 8) = v;
    }
  }
}

// ---------------- core: R13 minimal-fence ring GEMM + &15 swizzle, split-K(q)=8 ----------------
// Grid 256 (1 block/CU). Block 128p x 256b, 8 waves (2x4), wave 64p x 64b.
// LDS: A ring 3 x 32KB ([128p][128r] bf16, &15-swizzled) + x1 [16q][256b] f32 16KB.
__global__ __launch_bounds__(512, 2) void k_core(const unsigned short* __restrict__ Gbf,  // [128][16384]
                                                 const float* __restrict__ UX1,           // [128][8192]
                                                 const unsigned short* __restrict__ UX2T, // [8192][128]
                                                 unsigned short* __restrict__ PT){        // [8][8192][128] bf16
  __shared__ __align__(16) unsigned char lds[114688];      // 3x32K ring + 16K x1
  unsigned char* ldsX = lds + 98304;
  const int tid = threadIdx.x, lane = tid & 63, wv = tid >> 6;
  const int g = lane >> 4, l15 = lane & 15;
  const int wr = wv >> 2, wc = wv & 3;          // 2 x 4 waves; wave 64p x 64b
  const int blk = blockIdx.x;                   // 0..255; round-robin => xcd = blk&7
  const int split = blk & 7;                    // one split per XCD (G slice 512KB, L2-res)
  const int b0 = (blk >> 3) * 256;              // 0..7936
  const int q0 = split * 16;

  // stage one 32KB q-slice [128p][128r] into ring buf (4 glds16 per wave).
  // &15 source pre-swizzle matches &15 read XOR (measured: 2.2M -> ~0.13M conflicts).
  auto stageA = [&](int q, int buf){
#pragma unroll
    for (int rnd = 0; rnd < 4; ++rnd){
      const int off = rnd * 8192 + wv * 1024 + lane * 16;
      const int row = off >> 8;                 // p-row 0..127
      const int ss = ((off >> 4) & 15) ^ (row & 15);  // source pre-swizzle
      glds16(Gbf + (size_t)row * 16384 + (size_t)q * 128 + ss * 8,
             lds + buf * 32768 + off);
    }
  };

  // B hoist FIRST: 16 bf8 = 64 VGPR, whole kernel
  bf8 Bf[4][4];
#pragma unroll
  for (int kc = 0; kc < 4; ++kc)
#pragma unroll
    for (int nf = 0; nf < 4; ++nf)
      Bf[kc][nf] = *(const bf8*)(UX2T + (size_t)(b0 + wc * 64 + nf * 16 + l15) * 128 +
                                 kc * 32 + g * 8);
  // x1 slice [16q][256b] f32 -> LDS (2 glds)
#pragma unroll
  for (int rnd = 0; rnd < 2; ++rnd){
    const int off = rnd * 8192 + wv * 1024 + lane * 16;
    const int row = off >> 10;                  // q-row 0..15
    glds16(UX1 + (size_t)(q0 + row) * 8192 + b0 + ((off >> 2) & 255), ldsX + off);
  }
  stageA(q0 + 0, 0);
  stageA(q0 + 1, 1);

  f4 acc[4][4];
#pragma unroll
  for (int mf = 0; mf < 4; ++mf)
#pragma unroll
    for (int nf = 0; nf < 4; ++nf) acc[mf][nf] = (f4){0.f, 0.f, 0.f, 0.f};

  int cur = 0;                                  // ring buffer of body(i)
  for (int i = 0; i < 16; ++i){
    // ONE counted wait + ONE barrier per q; nothing else pins the schedule.
    if (i < 15) asm volatile("s_waitcnt vmcnt(4)" ::: "memory");
    else        asm volatile("s_waitcnt vmcnt(0)" ::: "memory");
    __builtin_amdgcn_s_barrier();
    if (i < 14){
      int sbuf = cur + 2; if (sbuf >= 3) sbuf -= 3;
      stageA(q0 + i + 2, sbuf);
    }

    // ---- body: pure C++, compiler-scheduled (fine lgkmcnt, MFMA interleave)
    const unsigned char* A = lds + cur * 32768;
    float xs[4];
#pragma unroll
    for (int nf = 0; nf < 4; ++nf)
      xs[nf] = *(const float*)(ldsX + i * 1024 + (wc * 64 + nf * 16 + l15) * 4);
#pragma unroll
    for (int mf = 0; mf < 4; ++mf){
      const int row = wr * 64 + mf * 16 + l15;  // row & 15 == l15
      bf8 a[4];
#pragma unroll
      for (int kc = 0; kc < 4; ++kc)
        a[kc] = *(const bf8*)(A + row * 256 + ((((kc << 2) + g) ^ l15) << 4));
#pragma unroll
      for (int nf = 0; nf < 4; ++nf){
        f4 y = __builtin_amdgcn_mfma_f32_16x16x32_bf16(a[0], Bf[0][nf], (f4){0.f,0.f,0.f,0.f}, 0, 0, 0);
        y = __builtin_amdgcn_mfma_f32_16x16x32_bf16(a[1], Bf[1][nf], y, 0, 0, 0);
        y = __builtin_amdgcn_mfma_f32_16x16x32_bf16(a[2], Bf[2][nf], y, 0, 0, 0);
        y = __builtin_amdgcn_mfma_f32_16x16x32_bf16(a[3], Bf[3][nf], y, 0, 0, 0);
        acc[mf][nf] += y * xs[nf];              // fold x1 in f32 (indep chain tail)
      }
    }
    ++cur; if (cur == 3) cur = 0;
  }

  // epilogue: acc -> PT[split][b][p] bf16 via swizzled LDS transpose (64KB in ring)
  __syncthreads();
#pragma unroll
  for (int mf = 0; mf < 4; ++mf)
#pragma unroll
    for (int nf = 0; nf < 4; ++nf){
      const int bL = wc * 64 + nf * 16 + l15;    // 0..255
      const int pq = wr * 16 + mf * 4 + g;       // p-quad 0..31
      bf4 o;
#pragma unroll
      for (int j = 0; j < 4; ++j) o[j] = (short)f2bf(acc[mf][nf][j]);
      *(bf4*)(lds + bL * 256 + ((pq ^ (bL & 7)) << 3)) = o;
    }
  __syncthreads();
#pragma unroll
  for (int rnd = 0; rnd < 8; ++rnd){
    const int idx = rnd * 512 + tid;             // 4096 x 16B chunks
    const int bL = idx >> 4, s8 = idx & 15;
    bf4 lo = *(const bf4*)(lds + bL * 256 + (((s8 * 2) ^ (bL & 7)) << 3));
    bf4 hi = *(const bf4*)(lds + bL * 256 + (((s8 * 2 + 1) ^ (bL & 7)) << 3));
    bf8 o;
#pragma unroll
    for (int j = 0; j < 4; ++j){ o[j] = lo[j]; o[4 + j] = hi[j]; }
    *(bf8*)(PT + (size_t)split * 1048576 + (size_t)(b0 + bL) * 128 + s8 * 8) = o;
  }
}

// ---------------- fused reduce + Z GEMM (256 blocks, 32-b columns) ----------------
__global__ __launch_bounds__(512, 1) void k_zred(const unsigned short* __restrict__ U0bf, // [512][128]
                                                 const unsigned short* __restrict__ PT,   // [8][8192][128]
                                                 float* __restrict__ Z){                  // [512][8192]
  __shared__ __align__(16) unsigned char ldsB[8192];       // [32b][128k] bf16 swizzled
  const int tid = threadIdx.x, lane = tid & 63, wv = tid >> 6;
  const int g = lane >> 4, l15 = lane & 15;
  const int b0 = blockIdx.x * 32;

  // (1) reduce: thread t -> b = t>>4 (0..31), slot = t&15 (8 k-elems each)
  {
    const int b = tid >> 4, slot = tid & 15;
    float s[8] = {0.f, 0.f, 0.f, 0.f, 0.f, 0.f, 0.f, 0.f};
#pragma unroll
    for (int sp = 0; sp < 8; ++sp){
      bf8 v = *(const bf8*)(PT + ((size_t)sp * 8192 + b0 + b) * 128 + slot * 8);
#pragma unroll
      for (int j = 0; j < 8; ++j) s[j] += bf2f((unsigned short)v[j]);
    }
    bf8 o;
#pragma unroll
    for (int j = 0; j < 8; ++j) o[j] = (short)f2bf(s[j]);
    *(bf8*)(ldsB + b * 256 + ((slot ^ (b & 15)) << 4)) = o;
  }

  // (2) A frags: wave wv owns d-rows [wv*64, wv*64+64); 16 bf8 = 64 VGPR
  bf8 a[4][4];                                   // [mf][kc]
#pragma unroll
  for (int mf = 0; mf < 4; ++mf)
#pragma unroll
    for (int kc = 0; kc < 4; ++kc)
      a[mf][kc] = *(const bf8*)(U0bf + (size_t)(wv * 64 + mf * 16 + l15) * 128 +
                                kc * 32 + g * 8);

  __syncthreads();

  // (3) GEMM: K=128 (4 kc), wave tile 64d x 32b (mf=4, nf=2)
  f4 acc[4][2];
#pragma unroll
  for (int nf = 0; nf < 2; ++nf){
    bf8 bfr[4];
    const int row = nf * 16 + l15;
#pragma unroll
    for (int kc = 0; kc < 4; ++kc)
      bfr[kc] = *(const bf8*)(ldsB + row * 256 + ((((kc << 2) + g) ^ (row & 15)) << 4));
#pragma unroll
    for (int mf = 0; mf < 4; ++mf){
      f4 y = __builtin_amdgcn_mfma_f32_16x16x32_bf16(a[mf][0], bfr[0], (f4){0.f,0.f,0.f,0.f}, 0, 0, 0);
      y = __builtin_amdgcn_mfma_f32_16x16x32_bf16(a[mf][1], bfr[1], y, 0, 0, 0);
      y = __builtin_amdgcn_mfma_f32_16x16x32_bf16(a[mf][2], bfr[2], y, 0, 0, 0);
      y = __builtin_amdgcn_mfma_f32_16x16x32_bf16(a[mf][3], bfr[3], y, 0, 0, 0);
      acc[mf][nf] = y;
    }
  }

  // (4) store Z[d][b] f32 (C/D: b-col = l15, d-rows = g*4+j)
#pragma unroll
  for (int mf = 0; mf < 4; ++mf)
#pragma unroll
    for (int nf = 0; nf < 2; ++nf)
#pragma unroll
      for (int j = 0; j < 4; ++j){
        const int d = wv * 64 + mf * 16 + g * 4 + j;
        const int b = b0 + nf * 16 + l15;
        Z[(size_t)d * 8192 + b] = acc[mf][nf][j];
      }
}

// ---------------- host launch ----------------
extern "C" void kernel_launch(void* const* d_in, const int* in_sizes, int n_in,
                              void* d_out, int out_size, void* d_ws, size_t ws_size,
                              hipStream_t stream){
  const float* X1 = (const float*)d_in[0];
  const float* X2 = (const float*)d_in[1];
  const float* U0 = (const float*)d_in[2];
  const float* U1 = (const float*)d_in[3];
  const float* U2 = (const float*)d_in[4];
  const float* G  = (const float*)d_in[5];
  float* Z = (float*)d_out;

  char* ws = (char*)d_ws;
  unsigned short* Gbf   = (unsigned short*)(ws);              //  4,194,304 B
  unsigned short* U0bf  = (unsigned short*)(ws + 4194304);    //    131,072 B
  unsigned short* U1T   = (unsigned short*)(ws + 4325376);    //    131,072 B
  unsigned short* U2T   = (unsigned short*)(ws + 4456448);    //    131,072 B
  float*          UX1   = (float*)         (ws + 4587520);    //  4,194,304 B
  unsigned short* UX2T  = (unsigned short*)(ws + 8781824);    //  2,097,152 B
  unsigned short* PT    = (unsigned short*)(ws + 12976128);   // 16,777,216 B (bf16 x8 splits)

  k_cast<<<dim3(2624), dim3(256), 0, stream>>>(G, U0, U1, U2, Gbf, U0bf, U1T, U2T);
  k_ux2 <<<dim3(128, 2), dim3(256), 0, stream>>>(U1T, U2T, X1, X2, UX1, UX2T);
  k_core<<<dim3(256), dim3(512), 0, stream>>>(Gbf, UX1, UX2T, PT);
  k_zred<<<dim3(256), dim3(512), 0, stream>>>(U0bf, PT, Z);
}